// Round 11
// baseline (99.578 us; speedup 1.0000x reference)
//
#include <hip/hip_runtime.h>
#include <hip/hip_bf16.h>

// B=256, N=10000, E=160000, H1=1024, H2=128
// - int inputs are int32; zeroing via kernels (graph-replay-safe)
// - GCN agg via dst-ELL gather (width 64, avg deg 16), atomic-free
// - bf16 MFMA gemm1 (128x128 tile, 8 waves, global_load_lds dbuf)
// - Round 11: fix r10's vmcnt bug. vmcnt counts WAVE-level outstanding
//   vector-mem instructions; 4 gll16/step/wave -> steady state 8 outstanding,
//   so vmcnt(8) waited for NOTHING (stale LDS, absmax 38). Correct: vmcnt(4).

#define KPAD 10240
#define NSTEPS 10   // K-steps of 64: KCHUNK = 640
#define ZSPLIT 16
#define ELLW 64

typedef __attribute__((ext_vector_type(8))) short short8v;   // 8 bf16
typedef __attribute__((ext_vector_type(4))) float f32x4;

__device__ inline short f2bf(float f) {  // RNE fp32->bf16
    union { float f; unsigned u; } v; v.f = f;
    unsigned r = v.u + 0x7fffu + ((v.u >> 16) & 1u);
    return (short)(r >> 16);
}

__device__ inline float bf2f(short s) {
    union { unsigned u; float f; } v;
    v.u = ((unsigned)(unsigned short)s) << 16;
    return v.f;
}

__device__ inline void gll16(const short* g, short* l) {
    __builtin_amdgcn_global_load_lds(
        (const __attribute__((address_space(1))) void*)g,
        (__attribute__((address_space(3))) void*)l, 16, 0, 0);
}

// fused: transpose_scale (data->xwT bf16) | convertB (W1->W1T bf16) | zero cnt
__global__ void pack_kernel(const float* __restrict__ data, const float* __restrict__ gw,
                            short* __restrict__ xwT, const float* __restrict__ W1,
                            short* __restrict__ W1T, float4* __restrict__ cntz,
                            int N, int B, int H1, int tTiles, int cTiles) {
    __shared__ short tile[32][66];
    int id = blockIdx.x, t = threadIdx.x;
    if (id < tTiles) {
        int nt = (N + 31) >> 5;
        int xb = id % nt, yb = id / nt;
        int n0 = xb * 32, b0 = yb * 32;
        float w = gw[0];
        int tx = t & 31, ty = t >> 5;
#pragma unroll
        for (int i = 0; i < 4; ++i) {
            int b = b0 + ty + i * 8;
            int n = n0 + tx;
            float v = (n < N) ? data[(size_t)b * N + n] : 0.f;
            tile[ty + i * 8][tx] = f2bf(v * w);
        }
        __syncthreads();
#pragma unroll
        for (int i = 0; i < 4; ++i) {
            int n = n0 + ty + i * 8;
            if (n < N) xwT[(size_t)n * B + b0 + tx] = tile[tx][ty + i * 8];
        }
    } else if (id < tTiles + cTiles) {
        int c = id - tTiles;
        int nk = KPAD >> 6;
        int kx = c % nk, hy = c / nk;
        int k0 = kx * 64, h0 = hy * 32;
        int hl = t & 31, kr = t >> 5;
#pragma unroll
        for (int i = 0; i < 8; ++i) {
            int k = k0 + kr + i * 8;
            float v = (k < N) ? W1[(size_t)k * H1 + h0 + hl] : 0.f;
            tile[hl][kr + i * 8] = f2bf(v);
        }
        __syncthreads();
        int kl = t & 63, hr = t >> 6;
#pragma unroll
        for (int i = 0; i < 8; ++i) {
            int h = h0 + hr + i * 4;
            W1T[(size_t)h * KPAD + k0 + kl] = tile[hr + i * 4][kl];
        }
    } else {
        int i = (id - tTiles - cTiles) * 256 + t;
        cntz[i] = make_float4(0.f, 0.f, 0.f, 0.f);
    }
}

__global__ void ell_fill(const int* __restrict__ ei, int* __restrict__ cnt,
                         int* __restrict__ ell, int E) {
    int e = blockIdx.x * blockDim.x + threadIdx.x;
    if (e >= E) return;
    int s = ei[e], d = ei[E + e];
    int c = atomicAdd(&cnt[d], 1);
    if (c < ELLW) ell[(d << 6) + c] = s;   // clamp is defensive; never hit
}

// one wave per dst row; A0[row][m] = bf16(relu(agg + gcn_b)); unroll-4
__global__ void gather_kernel(const int* __restrict__ cnt, const int* __restrict__ ell,
                              const float* __restrict__ gcn_b, const short* __restrict__ xwT,
                              short* __restrict__ A0, int N, int B) {
    int row = blockIdx.x * 4 + (threadIdx.x >> 6);
    if (row >= N) return;
    int lane = threadIdx.x & 63;
    const short4* x4 = (const short4*)xwT;
    const int B4 = B >> 2;
    float gb = gcn_b[0];
    int dcnt = cnt[row];
    float di = rsqrtf((float)dcnt + 1.0f);
    float w = di * di;
    short4 v = x4[(size_t)row * B4 + lane];
    float ax = bf2f(v.x) * w, ay = bf2f(v.y) * w, az = bf2f(v.z) * w, aw = bf2f(v.w) * w;
    const int* er = ell + ((size_t)row << 6);
    int m = dcnt < ELLW ? dcnt : ELLW;
    int i = 0;
    for (; i + 3 < m; i += 4) {
        int s0 = er[i], s1 = er[i + 1], s2 = er[i + 2], s3 = er[i + 3];
        float n0 = rsqrtf((float)cnt[s0] + 1.0f) * di;
        float n1 = rsqrtf((float)cnt[s1] + 1.0f) * di;
        float n2 = rsqrtf((float)cnt[s2] + 1.0f) * di;
        float n3 = rsqrtf((float)cnt[s3] + 1.0f) * di;
        short4 u0 = x4[(size_t)s0 * B4 + lane];
        short4 u1 = x4[(size_t)s1 * B4 + lane];
        short4 u2 = x4[(size_t)s2 * B4 + lane];
        short4 u3 = x4[(size_t)s3 * B4 + lane];
        ax = fmaf(bf2f(u0.x), n0, ax); ay = fmaf(bf2f(u0.y), n0, ay);
        az = fmaf(bf2f(u0.z), n0, az); aw = fmaf(bf2f(u0.w), n0, aw);
        ax = fmaf(bf2f(u1.x), n1, ax); ay = fmaf(bf2f(u1.y), n1, ay);
        az = fmaf(bf2f(u1.z), n1, az); aw = fmaf(bf2f(u1.w), n1, aw);
        ax = fmaf(bf2f(u2.x), n2, ax); ay = fmaf(bf2f(u2.y), n2, ay);
        az = fmaf(bf2f(u2.z), n2, az); aw = fmaf(bf2f(u2.w), n2, aw);
        ax = fmaf(bf2f(u3.x), n3, ax); ay = fmaf(bf2f(u3.y), n3, ay);
        az = fmaf(bf2f(u3.z), n3, az); aw = fmaf(bf2f(u3.w), n3, aw);
    }
    for (; i + 1 < m; i += 2) {
        int s0 = er[i], s1 = er[i + 1];
        float n0 = rsqrtf((float)cnt[s0] + 1.0f) * di;
        float n1 = rsqrtf((float)cnt[s1] + 1.0f) * di;
        short4 u0 = x4[(size_t)s0 * B4 + lane];
        short4 u1 = x4[(size_t)s1 * B4 + lane];
        ax = fmaf(bf2f(u0.x), n0, ax); ay = fmaf(bf2f(u0.y), n0, ay);
        az = fmaf(bf2f(u0.z), n0, az); aw = fmaf(bf2f(u0.w), n0, aw);
        ax = fmaf(bf2f(u1.x), n1, ax); ay = fmaf(bf2f(u1.y), n1, ay);
        az = fmaf(bf2f(u1.z), n1, az); aw = fmaf(bf2f(u1.w), n1, aw);
    }
    if (i < m) {
        int s0 = er[i];
        float n0 = rsqrtf((float)cnt[s0] + 1.0f) * di;
        short4 u0 = x4[(size_t)s0 * B4 + lane];
        ax = fmaf(bf2f(u0.x), n0, ax); ay = fmaf(bf2f(u0.y), n0, ay);
        az = fmaf(bf2f(u0.z), n0, az); aw = fmaf(bf2f(u0.w), n0, aw);
    }
    short4 s4;
    s4.x = f2bf(fmaxf(ax + gb, 0.f));
    s4.y = f2bf(fmaxf(ay + gb, 0.f));
    s4.z = f2bf(fmaxf(az + gb, 0.f));
    s4.w = f2bf(fmaxf(aw + gb, 0.f));
    ((short4*)(A0 + (size_t)row * B))[lane] = s4;
}

// A0 [N][256] bf16 -> A [256][KPAD] bf16 (transpose, zero-pad k>=N)
__global__ void convertA(const short* __restrict__ A0, short* __restrict__ A, int K, int M) {
    __shared__ short tile[32][34];
    int k0 = blockIdx.x * 32, m0 = blockIdx.y * 32;
    int tx = threadIdx.x, ty = threadIdx.y;
#pragma unroll
    for (int i = 0; i < 4; ++i) {
        int k = k0 + ty + i * 8;
        short v = (k < K) ? A0[(size_t)k * M + m0 + tx] : (short)0;
        tile[tx][ty + i * 8] = v;
    }
    __syncthreads();
#pragma unroll
    for (int i = 0; i < 4; ++i) {
        int m = m0 + ty + i * 8;
        A[(size_t)m * KPAD + k0 + tx] = tile[ty + i * 8][tx];
    }
}

// bf16 MFMA split-K GEMM: hpart[z][m][n] = sum_k A[m][k] * W1T[n][k]
// 128x128 tile, 8 waves (2m x 4n), BK=64: 16 MFMA/step/wave, NSTEPS=10.
// LDS per operand per buf: [kq 0..7][row 0..127][8 shorts] = 16KB; dbuf.
// Staging: 4 gll16/wave/step; seg s (0..1023): row=s&127, kq=s>>7;
// LDS byte = s*16 = wave-uniform base + lane*16 (global_load_lds contract).
// vmcnt(4): drain the current step's 4 wave-level loads, keep 4 prefetch
// in flight (r10 bug: vmcnt(8) waited for nothing).
__global__ void __launch_bounds__(512)
gemm1_mfma(const short* __restrict__ A, const short* __restrict__ Wt,
           float* __restrict__ hpart) {
    __shared__ __align__(16) short ldsA[2][8192];
    __shared__ __align__(16) short ldsB[2][8192];
    const int n0 = blockIdx.x * 128;
    const int m0 = blockIdx.y * 128;
    const int kz = blockIdx.z * (NSTEPS * 64);
    const int t = threadIdx.x;            // 0..511
    const int l = t & 63, w = t >> 6;     // lane, wave 0..7
    const int wm = w >> 2, wn = w & 3;    // 2m x 4n wave grid
    const int q = l >> 4, i16 = l & 15;

    const int sRow = t & 127, sKq = t >> 7;              // group-0: kq 0..3
    const short* gA = A + (size_t)(m0 + sRow) * KPAD + kz + sKq * 8;
    const short* gB = Wt + (size_t)(n0 + sRow) * KPAD + kz + sKq * 8;
    const int ld0 = w * 512;              // shorts; group-1 at +4096 (kq 4..7)
    const int ld1 = 4096 + w * 512;

    f32x4 acc[4][2];
#pragma unroll
    for (int mi = 0; mi < 4; ++mi)
#pragma unroll
        for (int ni = 0; ni < 2; ++ni) acc[mi][ni] = (f32x4){0.f, 0.f, 0.f, 0.f};

    // prologue: stage step 0 into buf 0 (4 wave-level loads)
    gll16(gA, &ldsA[0][ld0]); gll16(gA + 32, &ldsA[0][ld1]);
    gll16(gB, &ldsB[0][ld0]); gll16(gB + 32, &ldsB[0][ld1]);
    gA += 64; gB += 64;

    for (int ks = 0; ks < NSTEPS; ++ks) {
        const int cur = ks & 1;
        if (ks + 1 < NSTEPS) {
            gll16(gA, &ldsA[cur ^ 1][ld0]); gll16(gA + 32, &ldsA[cur ^ 1][ld1]);
            gll16(gB, &ldsB[cur ^ 1][ld0]); gll16(gB + 32, &ldsB[cur ^ 1][ld1]);
            gA += 64; gB += 64;
            asm volatile("s_waitcnt vmcnt(4)" ::: "memory");  // cur 4 done, 4 prefetch in flight
        } else {
            asm volatile("s_waitcnt vmcnt(0)" ::: "memory");
        }
        __builtin_amdgcn_s_barrier();
        __builtin_amdgcn_sched_barrier(0);
        const short* bA = &ldsA[cur][0];
        const short* bB = &ldsB[cur][0];
#pragma unroll
        for (int kh = 0; kh < 2; ++kh) {
            const int kq = kh * 4 + q;
            short8v a[4], b[2];
#pragma unroll
            for (int mi = 0; mi < 4; ++mi)
                a[mi] = *(const short8v*)&bA[kq * 1024 + (wm * 64 + mi * 16 + i16) * 8];
#pragma unroll
            for (int ni = 0; ni < 2; ++ni)
                b[ni] = *(const short8v*)&bB[kq * 1024 + (wn * 32 + ni * 16 + i16) * 8];
#pragma unroll
            for (int mi = 0; mi < 4; ++mi)
#pragma unroll
                for (int ni = 0; ni < 2; ++ni)
                    acc[mi][ni] = __builtin_amdgcn_mfma_f32_16x16x32_bf16(a[mi], b[ni], acc[mi][ni], 0, 0, 0);
        }
        __builtin_amdgcn_s_barrier();
    }

    // C/D layout (HW-verified): col = lane&15, row = (lane>>4)*4 + reg
    float* hp = hpart + (size_t)blockIdx.z * (256 * 1024);
#pragma unroll
    for (int mi = 0; mi < 4; ++mi) {
#pragma unroll
        for (int ni = 0; ni < 2; ++ni) {
#pragma unroll
            for (int r = 0; r < 4; ++r) {
                int mr = m0 + wm * 64 + mi * 16 + q * 4 + r;
                int nc = n0 + wn * 32 + ni * 16 + i16;
                hp[(size_t)mr * 1024 + nc] = acc[mi][ni][r];
            }
        }
    }
}

// fused: 4 batch rows per block. h[r][t]=relu(sum_z hpart+b1); out=relu(h.W2+b2)
// W2 element loaded once, reused for 4 rows (W2 L2 traffic /4).
__global__ void gemm2_fused(const float* __restrict__ hpart, const float* __restrict__ b1,
                            const float* __restrict__ W2, const float* __restrict__ b2,
                            float* __restrict__ out, int Z) {
    __shared__ float h_lds[4][1024];
    __shared__ float partial[8][4][128];
    int b0 = blockIdx.x * 4, t = threadIdx.x;
#pragma unroll
    for (int i = 0; i < 4; ++i) {
        int e = t + i * 1024;
        int row = e >> 10, col = e & 1023;
        float s = 0.f;
        for (int z = 0; z < Z; ++z)
            s += hpart[(size_t)z * (256 * 1024) + (size_t)(b0 + row) * 1024 + col];
        h_lds[row][col] = fmaxf(s + b1[col], 0.f);
    }
    __syncthreads();
    int j = t & 127, oct = t >> 7;
    const float* w2p = W2 + (size_t)oct * 128 * 128 + j;
    const float* hp = &h_lds[0][oct * 128];
    float s0 = 0.f, s1 = 0.f, s2 = 0.f, s3 = 0.f;
#pragma unroll 4
    for (int k = 0; k < 128; ++k) {
        float wv = w2p[(size_t)k * 128];
        s0 = fmaf(hp[k],        wv, s0);
        s1 = fmaf(hp[k + 1024], wv, s1);
        s2 = fmaf(hp[k + 2048], wv, s2);
        s3 = fmaf(hp[k + 3072], wv, s3);
    }
    partial[oct][0][j] = s0; partial[oct][1][j] = s1;
    partial[oct][2][j] = s2; partial[oct][3][j] = s3;
    __syncthreads();
    if (t < 512) {
        int row = t >> 7, jj = t & 127;
        float v = b2[jj];
#pragma unroll
        for (int o = 0; o < 8; ++o) v += partial[o][row][jj];
        out[(size_t)(b0 + row) * 128 + jj] = fmaxf(v, 0.f);
    }
}

extern "C" void kernel_launch(void* const* d_in, const int* in_sizes, int n_in,
                              void* d_out, int out_size, void* d_ws, size_t ws_size,
                              hipStream_t stream) {
    const float* data = (const float*)d_in[0];
    const float* gw   = (const float*)d_in[1];
    const float* gb   = (const float*)d_in[2];
    const float* W1   = (const float*)d_in[3];
    const float* b1   = (const float*)d_in[4];
    const float* W2   = (const float*)d_in[5];
    const float* b2   = (const float*)d_in[6];
    const int*   ei   = (const int*)d_in[7];
    float* out = (float*)d_out;

    const int B  = 256;
    const int H1 = in_sizes[4];          // 1024
    const int H2 = in_sizes[6];          // 128
    const int N  = in_sizes[3] / H1;     // 10000
    const int E  = in_sizes[7] / 2;      // 160000
    const int NP = 10240;

    int* iws = (int*)d_ws;
    int*   cnt  = iws;                               // NP ints
    int*   ell  = cnt + NP;                          // NP*ELLW ints
    short* S    = (short*)(ell + (size_t)NP * ELLW);
    short* A    = S;                                 // 256*KPAD
    short* W1T  = A + (size_t)256 * KPAD;            // 1024*KPAD
    short* xwT  = W1T + (size_t)1024 * KPAD;         // N*B
    short* A0   = xwT + (size_t)N * B;               // N*B
    float* hpart = (float*)xwT;                      // ZSPLIT*256*1024 f32 (overlays xwT/A0+)

    const int tTiles = ((N + 31) / 32) * (B / 32);       // 2504
    const int cTiles = (KPAD / 64) * (H1 / 32);          // 5120
    const int zBlks  = NP / 1024;                        // 10

    pack_kernel<<<tTiles + cTiles + zBlks, 256, 0, stream>>>(
        data, gw, xwT, W1, W1T, (float4*)cnt, N, B, H1, tTiles, cTiles);

    ell_fill<<<(E + 255) / 256, 256, 0, stream>>>(ei, cnt, ell, E);

    gather_kernel<<<(N + 3) / 4, 256, 0, stream>>>(cnt, ell, gb, xwT, A0, N, B);

    convertA<<<dim3(KPAD / 32, B / 32), dim3(32, 8), 0, stream>>>(A0, A, N, B);

    dim3 g1(H1 / 128, B / 128, ZSPLIT);   // 8 x 2 x 16 = 256 blocks
    gemm1_mfma<<<g1, 512, 0, stream>>>(A, W1T, hpart);

    gemm2_fused<<<B / 4, 1024, 0, stream>>>(hpart, b1, W2, b2, out, ZSPLIT);
}

// Round 12
// 88.000 us; speedup vs baseline: 1.1316x; 1.1316x over previous
//
#include <hip/hip_runtime.h>
#include <hip/hip_bf16.h>

// B=256, N=10000, E=160000, H1=1024, H2=128
// - int inputs are int32; zeroing via kernels (graph-replay-safe)
// - GCN agg via dst-ELL gather (width 64, avg deg 16), atomic-free
// - bf16 MFMA gemm1 (128x128 tile, 8 waves, global_load_lds dbuf)
// - Round 12: ATTRIBUTION round. r10 bundle (+9us vs r9): revert gemm2 to
//   1-row/256-block (r10's 64-block grid idled 192 CUs) and gather to
//   unroll-2 (r9 exact); KEEP gemm1 BK=64 + vmcnt(4) (halved barriers,
//   sound theory). If this lands ~86us, gemm2/gather were the regression;
//   if ~99, gemm1-BK64 is and r13 reverts it.

#define KPAD 10240
#define NSTEPS 10   // K-steps of 64: KCHUNK = 640
#define ZSPLIT 16
#define ELLW 64

typedef __attribute__((ext_vector_type(8))) short short8v;   // 8 bf16
typedef __attribute__((ext_vector_type(4))) float f32x4;

__device__ inline short f2bf(float f) {  // RNE fp32->bf16
    union { float f; unsigned u; } v; v.f = f;
    unsigned r = v.u + 0x7fffu + ((v.u >> 16) & 1u);
    return (short)(r >> 16);
}

__device__ inline float bf2f(short s) {
    union { unsigned u; float f; } v;
    v.u = ((unsigned)(unsigned short)s) << 16;
    return v.f;
}

__device__ inline void gll16(const short* g, short* l) {
    __builtin_amdgcn_global_load_lds(
        (const __attribute__((address_space(1))) void*)g,
        (__attribute__((address_space(3))) void*)l, 16, 0, 0);
}

// fused: transpose_scale (data->xwT bf16) | convertB (W1->W1T bf16) | zero cnt
__global__ void pack_kernel(const float* __restrict__ data, const float* __restrict__ gw,
                            short* __restrict__ xwT, const float* __restrict__ W1,
                            short* __restrict__ W1T, float4* __restrict__ cntz,
                            int N, int B, int H1, int tTiles, int cTiles) {
    __shared__ short tile[32][66];
    int id = blockIdx.x, t = threadIdx.x;
    if (id < tTiles) {
        int nt = (N + 31) >> 5;
        int xb = id % nt, yb = id / nt;
        int n0 = xb * 32, b0 = yb * 32;
        float w = gw[0];
        int tx = t & 31, ty = t >> 5;
#pragma unroll
        for (int i = 0; i < 4; ++i) {
            int b = b0 + ty + i * 8;
            int n = n0 + tx;
            float v = (n < N) ? data[(size_t)b * N + n] : 0.f;
            tile[ty + i * 8][tx] = f2bf(v * w);
        }
        __syncthreads();
#pragma unroll
        for (int i = 0; i < 4; ++i) {
            int n = n0 + ty + i * 8;
            if (n < N) xwT[(size_t)n * B + b0 + tx] = tile[tx][ty + i * 8];
        }
    } else if (id < tTiles + cTiles) {
        int c = id - tTiles;
        int nk = KPAD >> 6;
        int kx = c % nk, hy = c / nk;
        int k0 = kx * 64, h0 = hy * 32;
        int hl = t & 31, kr = t >> 5;
#pragma unroll
        for (int i = 0; i < 8; ++i) {
            int k = k0 + kr + i * 8;
            float v = (k < N) ? W1[(size_t)k * H1 + h0 + hl] : 0.f;
            tile[hl][kr + i * 8] = f2bf(v);
        }
        __syncthreads();
        int kl = t & 63, hr = t >> 6;
#pragma unroll
        for (int i = 0; i < 8; ++i) {
            int h = h0 + hr + i * 4;
            W1T[(size_t)h * KPAD + k0 + kl] = tile[hr + i * 4][kl];
        }
    } else {
        int i = (id - tTiles - cTiles) * 256 + t;
        cntz[i] = make_float4(0.f, 0.f, 0.f, 0.f);
    }
}

__global__ void ell_fill(const int* __restrict__ ei, int* __restrict__ cnt,
                         int* __restrict__ ell, int E) {
    int e = blockIdx.x * blockDim.x + threadIdx.x;
    if (e >= E) return;
    int s = ei[e], d = ei[E + e];
    int c = atomicAdd(&cnt[d], 1);
    if (c < ELLW) ell[(d << 6) + c] = s;   // clamp is defensive; never hit
}

// one wave per dst row; A0[row][m] = bf16(relu(agg + gcn_b)); unroll-2 (r9)
__global__ void gather_kernel(const int* __restrict__ cnt, const int* __restrict__ ell,
                              const float* __restrict__ gcn_b, const short* __restrict__ xwT,
                              short* __restrict__ A0, int N, int B) {
    int row = blockIdx.x * 4 + (threadIdx.x >> 6);
    if (row >= N) return;
    int lane = threadIdx.x & 63;
    const short4* x4 = (const short4*)xwT;
    const int B4 = B >> 2;
    float gb = gcn_b[0];
    int dcnt = cnt[row];
    float di = rsqrtf((float)dcnt + 1.0f);
    float w = di * di;
    short4 v = x4[(size_t)row * B4 + lane];
    float ax = bf2f(v.x) * w, ay = bf2f(v.y) * w, az = bf2f(v.z) * w, aw = bf2f(v.w) * w;
    const int* er = ell + ((size_t)row << 6);
    int m = dcnt < ELLW ? dcnt : ELLW;
    int i = 0;
    for (; i + 1 < m; i += 2) {
        int s0 = er[i], s1 = er[i + 1];
        float n0 = rsqrtf((float)cnt[s0] + 1.0f) * di;
        float n1 = rsqrtf((float)cnt[s1] + 1.0f) * di;
        short4 u0 = x4[(size_t)s0 * B4 + lane];
        short4 u1 = x4[(size_t)s1 * B4 + lane];
        ax = fmaf(bf2f(u0.x), n0, ax); ay = fmaf(bf2f(u0.y), n0, ay);
        az = fmaf(bf2f(u0.z), n0, az); aw = fmaf(bf2f(u0.w), n0, aw);
        ax = fmaf(bf2f(u1.x), n1, ax); ay = fmaf(bf2f(u1.y), n1, ay);
        az = fmaf(bf2f(u1.z), n1, az); aw = fmaf(bf2f(u1.w), n1, aw);
    }
    if (i < m) {
        int s0 = er[i];
        float n0 = rsqrtf((float)cnt[s0] + 1.0f) * di;
        short4 u0 = x4[(size_t)s0 * B4 + lane];
        ax = fmaf(bf2f(u0.x), n0, ax); ay = fmaf(bf2f(u0.y), n0, ay);
        az = fmaf(bf2f(u0.z), n0, az); aw = fmaf(bf2f(u0.w), n0, aw);
    }
    short4 s4;
    s4.x = f2bf(fmaxf(ax + gb, 0.f));
    s4.y = f2bf(fmaxf(ay + gb, 0.f));
    s4.z = f2bf(fmaxf(az + gb, 0.f));
    s4.w = f2bf(fmaxf(aw + gb, 0.f));
    ((short4*)(A0 + (size_t)row * B))[lane] = s4;
}

// A0 [N][256] bf16 -> A [256][KPAD] bf16 (transpose, zero-pad k>=N)
__global__ void convertA(const short* __restrict__ A0, short* __restrict__ A, int K, int M) {
    __shared__ short tile[32][34];
    int k0 = blockIdx.x * 32, m0 = blockIdx.y * 32;
    int tx = threadIdx.x, ty = threadIdx.y;
#pragma unroll
    for (int i = 0; i < 4; ++i) {
        int k = k0 + ty + i * 8;
        short v = (k < K) ? A0[(size_t)k * M + m0 + tx] : (short)0;
        tile[tx][ty + i * 8] = v;
    }
    __syncthreads();
#pragma unroll
    for (int i = 0; i < 4; ++i) {
        int m = m0 + ty + i * 8;
        A[(size_t)m * KPAD + k0 + tx] = tile[ty + i * 8][tx];
    }
}

// bf16 MFMA split-K GEMM: hpart[z][m][n] = sum_k A[m][k] * W1T[n][k]
// 128x128 tile, 8 waves (2m x 4n), BK=64: 16 MFMA/step/wave, NSTEPS=10.
// vmcnt(4): drain the current step's 4 wave-level loads, keep 4 prefetch
// in flight (vmcnt counts wave-level outstanding vector-mem instructions).
__global__ void __launch_bounds__(512)
gemm1_mfma(const short* __restrict__ A, const short* __restrict__ Wt,
           float* __restrict__ hpart) {
    __shared__ __align__(16) short ldsA[2][8192];
    __shared__ __align__(16) short ldsB[2][8192];
    const int n0 = blockIdx.x * 128;
    const int m0 = blockIdx.y * 128;
    const int kz = blockIdx.z * (NSTEPS * 64);
    const int t = threadIdx.x;            // 0..511
    const int l = t & 63, w = t >> 6;     // lane, wave 0..7
    const int wm = w >> 2, wn = w & 3;    // 2m x 4n wave grid
    const int q = l >> 4, i16 = l & 15;

    const int sRow = t & 127, sKq = t >> 7;              // group-0: kq 0..3
    const short* gA = A + (size_t)(m0 + sRow) * KPAD + kz + sKq * 8;
    const short* gB = Wt + (size_t)(n0 + sRow) * KPAD + kz + sKq * 8;
    const int ld0 = w * 512;              // shorts; group-1 at +4096 (kq 4..7)
    const int ld1 = 4096 + w * 512;

    f32x4 acc[4][2];
#pragma unroll
    for (int mi = 0; mi < 4; ++mi)
#pragma unroll
        for (int ni = 0; ni < 2; ++ni) acc[mi][ni] = (f32x4){0.f, 0.f, 0.f, 0.f};

    // prologue: stage step 0 into buf 0 (4 wave-level loads)
    gll16(gA, &ldsA[0][ld0]); gll16(gA + 32, &ldsA[0][ld1]);
    gll16(gB, &ldsB[0][ld0]); gll16(gB + 32, &ldsB[0][ld1]);
    gA += 64; gB += 64;

    for (int ks = 0; ks < NSTEPS; ++ks) {
        const int cur = ks & 1;
        if (ks + 1 < NSTEPS) {
            gll16(gA, &ldsA[cur ^ 1][ld0]); gll16(gA + 32, &ldsA[cur ^ 1][ld1]);
            gll16(gB, &ldsB[cur ^ 1][ld0]); gll16(gB + 32, &ldsB[cur ^ 1][ld1]);
            gA += 64; gB += 64;
            asm volatile("s_waitcnt vmcnt(4)" ::: "memory");  // cur 4 done, 4 prefetch in flight
        } else {
            asm volatile("s_waitcnt vmcnt(0)" ::: "memory");
        }
        __builtin_amdgcn_s_barrier();
        __builtin_amdgcn_sched_barrier(0);
        const short* bA = &ldsA[cur][0];
        const short* bB = &ldsB[cur][0];
#pragma unroll
        for (int kh = 0; kh < 2; ++kh) {
            const int kq = kh * 4 + q;
            short8v a[4], b[2];
#pragma unroll
            for (int mi = 0; mi < 4; ++mi)
                a[mi] = *(const short8v*)&bA[kq * 1024 + (wm * 64 + mi * 16 + i16) * 8];
#pragma unroll
            for (int ni = 0; ni < 2; ++ni)
                b[ni] = *(const short8v*)&bB[kq * 1024 + (wn * 32 + ni * 16 + i16) * 8];
#pragma unroll
            for (int mi = 0; mi < 4; ++mi)
#pragma unroll
                for (int ni = 0; ni < 2; ++ni)
                    acc[mi][ni] = __builtin_amdgcn_mfma_f32_16x16x32_bf16(a[mi], b[ni], acc[mi][ni], 0, 0, 0);
        }
        __builtin_amdgcn_s_barrier();
    }

    // C/D layout (HW-verified): col = lane&15, row = (lane>>4)*4 + reg
    float* hp = hpart + (size_t)blockIdx.z * (256 * 1024);
#pragma unroll
    for (int mi = 0; mi < 4; ++mi) {
#pragma unroll
        for (int ni = 0; ni < 2; ++ni) {
#pragma unroll
            for (int r = 0; r < 4; ++r) {
                int mr = m0 + wm * 64 + mi * 16 + q * 4 + r;
                int nc = n0 + wn * 32 + ni * 16 + i16;
                hp[(size_t)mr * 1024 + nc] = acc[mi][ni][r];
            }
        }
    }
}

// fused (r9 exact): one block per batch row.
// h[t] = relu(sum_z hpart[z][b][t] + b1[t]); out[b][j] = relu(h . W2[:,j] + b2[j])
__global__ void gemm2_fused(const float* __restrict__ hpart, const float* __restrict__ b1,
                            const float* __restrict__ W2, const float* __restrict__ b2,
                            float* __restrict__ out, int Z) {
    __shared__ float h_lds[1024];
    __shared__ float partial[8][128];
    int b = blockIdx.x, t = threadIdx.x;
    float s = 0.f;
    for (int z = 0; z < Z; ++z) s += hpart[(size_t)z * (256 * 1024) + b * 1024 + t];
    h_lds[t] = fmaxf(s + b1[t], 0.f);
    __syncthreads();
    int j = t & 127, oct = t >> 7;
    const float* w2p = W2 + (size_t)oct * 128 * 128 + j;
    const float* hp = h_lds + oct * 128;
    float s0 = 0.f, s1 = 0.f, s2 = 0.f, s3 = 0.f;
#pragma unroll 8
    for (int k = 0; k < 128; k += 4) {
        s0 = fmaf(hp[k],     w2p[(size_t)k * 128],       s0);
        s1 = fmaf(hp[k + 1], w2p[(size_t)(k + 1) * 128], s1);
        s2 = fmaf(hp[k + 2], w2p[(size_t)(k + 2) * 128], s2);
        s3 = fmaf(hp[k + 3], w2p[(size_t)(k + 3) * 128], s3);
    }
    partial[oct][j] = (s0 + s1) + (s2 + s3);
    __syncthreads();
    if (t < 128) {
        float v = b2[t];
#pragma unroll
        for (int o = 0; o < 8; ++o) v += partial[o][t];
        out[(size_t)b * 128 + t] = fmaxf(v, 0.f);
    }
}

extern "C" void kernel_launch(void* const* d_in, const int* in_sizes, int n_in,
                              void* d_out, int out_size, void* d_ws, size_t ws_size,
                              hipStream_t stream) {
    const float* data = (const float*)d_in[0];
    const float* gw   = (const float*)d_in[1];
    const float* gb   = (const float*)d_in[2];
    const float* W1   = (const float*)d_in[3];
    const float* b1   = (const float*)d_in[4];
    const float* W2   = (const float*)d_in[5];
    const float* b2   = (const float*)d_in[6];
    const int*   ei   = (const int*)d_in[7];
    float* out = (float*)d_out;

    const int B  = 256;
    const int H1 = in_sizes[4];          // 1024
    const int H2 = in_sizes[6];          // 128
    const int N  = in_sizes[3] / H1;     // 10000
    const int E  = in_sizes[7] / 2;      // 160000
    const int NP = 10240;

    int* iws = (int*)d_ws;
    int*   cnt  = iws;                               // NP ints
    int*   ell  = cnt + NP;                          // NP*ELLW ints
    short* S    = (short*)(ell + (size_t)NP * ELLW);
    short* A    = S;                                 // 256*KPAD
    short* W1T  = A + (size_t)256 * KPAD;            // 1024*KPAD
    short* xwT  = W1T + (size_t)1024 * KPAD;         // N*B
    short* A0   = xwT + (size_t)N * B;               // N*B
    float* hpart = (float*)xwT;                      // ZSPLIT*256*1024 f32 (overlays xwT/A0+)

    const int tTiles = ((N + 31) / 32) * (B / 32);       // 2504
    const int cTiles = (KPAD / 64) * (H1 / 32);          // 5120
    const int zBlks  = NP / 1024;                        // 10

    pack_kernel<<<tTiles + cTiles + zBlks, 256, 0, stream>>>(
        data, gw, xwT, W1, W1T, (float4*)cnt, N, B, H1, tTiles, cTiles);

    ell_fill<<<(E + 255) / 256, 256, 0, stream>>>(ei, cnt, ell, E);

    gather_kernel<<<(N + 3) / 4, 256, 0, stream>>>(cnt, ell, gb, xwT, A0, N, B);

    convertA<<<dim3(KPAD / 32, B / 32), dim3(32, 8), 0, stream>>>(A0, A, N, B);

    dim3 g1(H1 / 128, B / 128, ZSPLIT);   // 8 x 2 x 16 = 256 blocks
    gemm1_mfma<<<g1, 512, 0, stream>>>(A, W1T, hpart);

    gemm2_fused<<<B, 1024, 0, stream>>>(hpart, b1, W2, b2, out, ZSPLIT);
}